// Round 24
// baseline (145.017 us; speedup 1.0000x reference)
//
#include <hip/hip_runtime.h>

#define NR 1024        // num rois
#define NFG 80         // fg classes
#define CC 81          // total classes
#define KDIM 2048
#define H1DIM 256
#define H3DIM 512
#define D4 324         // 4*81
#define NCOMB 768      // 256 + 512 combined output cols
#define SKD 8          // split-K for deltas GEMM (K=512 -> 64/chunk)

typedef unsigned long long u64;

// ---------------- main GEMM partials: P[ks][1024][768] = X @ [w1|w3] (K-chunk ks) ----------
// 4-wave blocks, wave wv owns KW=KB/4, BK=16 sub-tiles -> 8KB LDS/wave, 32KB/block.
// SK=8 lifts the grid cap (1536 blocks -> 5-6 blocks/CU -> ~20 waves/CU sharing the
// LDS pipe); SK=4 fallback if ws too small. Private per-wave LDS, no inner barriers;
// deterministic tree-combine epilogue. XCD-chunked swizzle.
template <int SK>
__global__ __launch_bounds__(256) void gemm_main_kernel(
    const float* __restrict__ X, const float* __restrict__ w1,
    const float* __restrict__ w3, float* __restrict__ P)
{
    constexpr int KB = KDIM / SK;          // per-block K
    constexpr int KW = KB / 4;             // per-wave K
    constexpr int KT = KW / 16;            // BK=16 tiles per wave
    constexpr int GRID = 12 * 16 * SK;
    const int bid = blockIdx.x;
    const int swz = (bid & 7) * (GRID / 8) + (bid >> 3);
    const int nb = swz % 12;
    const int mb = (swz / 12) & 15;
    const int ks = swz / 192;

    const float* B; int Ncols, colbase;
    if (nb < 4) { B = w1; Ncols = H1DIM; colbase = nb * 64; }
    else        { B = w3; Ncols = H3DIM; colbase = (nb - 4) * 64; }
    const int row0 = mb * 64;
    const int wv = threadIdx.x >> 6;       // 0..3
    const int lane = threadIdx.x & 63;
    const int kstart = ks * KB + wv * KW;

    __shared__ float L[4][2048];           // per-wave 8KB: [0..1023]=As(16x64 [k][m]), [1024..]=Bs
    float* Asw = L[wv];
    float* Bsw = L[wv] + 1024;

    const int tx = lane & 7;
    const int ty = lane >> 3;
    const int rg = lane & 15;
    const int kg = lane >> 4;
    const int brow = lane >> 4;
    const int bcol4 = (lane & 15) * 4;

    float acc[8][8] = {};
    float4 ca[4], cb[4];

#pragma unroll
    for (int rr = 0; rr < 4; rr++)
        ca[rr] = *reinterpret_cast<const float4*>(
            &X[(size_t)(row0 + rg * 4 + rr) * KDIM + kstart + kg * 4]);
#pragma unroll
    for (int j = 0; j < 4; j++)
        cb[j] = *reinterpret_cast<const float4*>(
            &B[(size_t)(kstart + brow + j * 4) * Ncols + colbase + bcol4]);

    for (int kt = 0; kt < KT; kt++) {
        {
            const int kb = kg * 4;
            float4 w0 = make_float4(ca[0].x, ca[1].x, ca[2].x, ca[3].x);
            float4 w1_ = make_float4(ca[0].y, ca[1].y, ca[2].y, ca[3].y);
            float4 w2_ = make_float4(ca[0].z, ca[1].z, ca[2].z, ca[3].z);
            float4 w3_ = make_float4(ca[0].w, ca[1].w, ca[2].w, ca[3].w);
            *reinterpret_cast<float4*>(&Asw[(kb + 0) * 64 + rg * 4]) = w0;
            *reinterpret_cast<float4*>(&Asw[(kb + 1) * 64 + rg * 4]) = w1_;
            *reinterpret_cast<float4*>(&Asw[(kb + 2) * 64 + rg * 4]) = w2_;
            *reinterpret_cast<float4*>(&Asw[(kb + 3) * 64 + rg * 4]) = w3_;
        }
#pragma unroll
        for (int j = 0; j < 4; j++)
            *reinterpret_cast<float4*>(&Bsw[(brow + j * 4) * 64 + bcol4]) = cb[j];

        if (kt < KT - 1) {
            const int kof = kstart + (kt + 1) * 16;
#pragma unroll
            for (int rr = 0; rr < 4; rr++)
                ca[rr] = *reinterpret_cast<const float4*>(
                    &X[(size_t)(row0 + rg * 4 + rr) * KDIM + kof + kg * 4]);
#pragma unroll
            for (int j = 0; j < 4; j++)
                cb[j] = *reinterpret_cast<const float4*>(
                    &B[(size_t)(kof + brow + j * 4) * Ncols + colbase + bcol4]);
        }

#pragma unroll 8
        for (int kk = 0; kk < 16; kk++) {
            float4 a0 = *reinterpret_cast<const float4*>(&Asw[kk * 64 + ty * 8]);
            float4 a1 = *reinterpret_cast<const float4*>(&Asw[kk * 64 + ty * 8 + 4]);
            float4 b0 = *reinterpret_cast<const float4*>(&Bsw[kk * 64 + tx * 8]);
            float4 b1 = *reinterpret_cast<const float4*>(&Bsw[kk * 64 + tx * 8 + 4]);
            float av[8] = {a0.x, a0.y, a0.z, a0.w, a1.x, a1.y, a1.z, a1.w};
            float bv[8] = {b0.x, b0.y, b0.z, b0.w, b1.x, b1.y, b1.z, b1.w};
#pragma unroll
            for (int i = 0; i < 8; i++)
#pragma unroll
                for (int j = 0; j < 8; j++)
                    acc[i][j] += av[i] * bv[j];
        }
    }

    // deterministic tree-combine: (w0+w1) + (w2+w3), then w0 stores.
    float* buf0 = &L[0][0];
    float* buf1 = &L[2][0];
    __syncthreads();
    if (wv == 1 || wv == 3) {
        float* dst = (wv == 1) ? buf0 : buf1;
#pragma unroll
        for (int i = 0; i < 8; i++) {
            const int row = ty * 8 + i;
            *reinterpret_cast<float4*>(&dst[row * 64 + tx * 8]) =
                make_float4(acc[i][0], acc[i][1], acc[i][2], acc[i][3]);
            *reinterpret_cast<float4*>(&dst[row * 64 + tx * 8 + 4]) =
                make_float4(acc[i][4], acc[i][5], acc[i][6], acc[i][7]);
        }
    }
    __syncthreads();
    if (wv == 0 || wv == 2) {
        const float* src = (wv == 0) ? buf0 : buf1;
#pragma unroll
        for (int i = 0; i < 8; i++) {
            const int row = ty * 8 + i;
            float4 c0 = *reinterpret_cast<const float4*>(&src[row * 64 + tx * 8]);
            float4 c1 = *reinterpret_cast<const float4*>(&src[row * 64 + tx * 8 + 4]);
            acc[i][0] += c0.x; acc[i][1] += c0.y; acc[i][2] += c0.z; acc[i][3] += c0.w;
            acc[i][4] += c1.x; acc[i][5] += c1.y; acc[i][6] += c1.z; acc[i][7] += c1.w;
        }
    }
    __syncthreads();
    if (wv == 2) {
#pragma unroll
        for (int i = 0; i < 8; i++) {
            const int row = ty * 8 + i;
            *reinterpret_cast<float4*>(&buf0[row * 64 + tx * 8]) =
                make_float4(acc[i][0], acc[i][1], acc[i][2], acc[i][3]);
            *reinterpret_cast<float4*>(&buf0[row * 64 + tx * 8 + 4]) =
                make_float4(acc[i][4], acc[i][5], acc[i][6], acc[i][7]);
        }
    }
    __syncthreads();
    if (wv == 0) {
        const int ccol = nb * 64 + tx * 8;
#pragma unroll
        for (int i = 0; i < 8; i++) {
            const int row = ty * 8 + i;
            float4 c0 = *reinterpret_cast<const float4*>(&buf0[row * 64 + tx * 8]);
            float4 c1 = *reinterpret_cast<const float4*>(&buf0[row * 64 + tx * 8 + 4]);
            float* pr = &P[((size_t)ks * NR + row0 + row) * NCOMB + ccol];
            *reinterpret_cast<float4*>(&pr[0]) = make_float4(
                acc[i][0] + c0.x, acc[i][1] + c0.y, acc[i][2] + c0.z, acc[i][3] + c0.w);
            *reinterpret_cast<float4*>(&pr[4]) = make_float4(
                acc[i][4] + c1.x, acc[i][5] + c1.y, acc[i][6] + c1.z, acc[i][7] + c1.w);
        }
    }
}

// ---------------- mid: blocks 0..1023 reduce H3; blocks 1024..2047 scores+softmax ----------
template <int SK>
__global__ __launch_bounds__(128) void mid_kernel(
    const float* __restrict__ P, const float* __restrict__ b1,
    const float* __restrict__ b3, const float* __restrict__ w2,
    const float* __restrict__ b2, float* __restrict__ H3,
    float* __restrict__ probs)
{
    const int t = threadIdx.x;

    if (blockIdx.x < 1024) {
        const int idx = blockIdx.x * 128 + t;
        const int row = idx / (H3DIM / 4);
        const int col = (idx % (H3DIM / 4)) * 4;
        const size_t off = (size_t)row * NCOMB + H1DIM + col;
        float4 s = *reinterpret_cast<const float4*>(&P[off]);
#pragma unroll
        for (int ksplit = 1; ksplit < SK; ksplit++) {
            float4 p = *reinterpret_cast<const float4*>(&P[(size_t)ksplit * NR * NCOMB + off]);
            s.x += p.x; s.y += p.y; s.z += p.z; s.w += p.w;
        }
        float4 bb = *reinterpret_cast<const float4*>(&b3[col]);
        s.x = fmaxf(s.x + bb.x, 0.f); s.y = fmaxf(s.y + bb.y, 0.f);
        s.z = fmaxf(s.z + bb.z, 0.f); s.w = fmaxf(s.w + bb.w, 0.f);
        *reinterpret_cast<float4*>(&H3[row * H3DIM + col]) = s;
        return;
    }

    const int r = blockIdx.x - 1024;
    __shared__ float h[H1DIM];
    __shared__ float lg[CC];
    __shared__ float red[128];

    for (int k = t; k < H1DIM; k += 128) {
        float s = P[(size_t)r * NCOMB + k];
#pragma unroll
        for (int ksplit = 1; ksplit < SK; ksplit++)
            s += P[((size_t)ksplit * NR + r) * NCOMB + k];
        h[k] = fmaxf(s + b1[k], 0.f);
    }
    __syncthreads();

    if (t < CC) {
        float acc = b2[t];
        for (int k = 0; k < H1DIM; k++) acc += h[k] * w2[k * CC + t];
        lg[t] = acc;
    }
    __syncthreads();

    red[t] = (t < CC) ? lg[t] : -1e30f;
    __syncthreads();
    for (int s = 64; s > 0; s >>= 1) {
        if (t < s) red[t] = fmaxf(red[t], red[t + s]);
        __syncthreads();
    }
    float mx = red[0];
    __syncthreads();

    float e = 0.f;
    if (t < CC) e = expf(lg[t] - mx);
    red[t] = e;
    __syncthreads();
    for (int s = 64; s > 0; s >>= 1) {
        if (t < s) red[t] += red[t + s];
        __syncthreads();
    }
    float sum = red[0];

    if (t >= 1 && t < CC) probs[(t - 1) * NR + r] = e / sum;
}

// ---------------- deltas GEMM partials: Pd[ks][1024][324] = H3 @ w4 ----------
__global__ __launch_bounds__(64) void gemm_delta_kernel(
    const float* __restrict__ H3, const float* __restrict__ w4, float* __restrict__ Pd)
{
    const int nb = blockIdx.x;
    const int mb = blockIdx.y;
    const int ks = blockIdx.z;
    const int colbase = nb * 64;
    const int row0 = mb * 64;
    const int kstart = ks * 64;

    __shared__ float As[32][64];
    __shared__ float Bs[32][64];
    const int t = threadIdx.x;
    const int tx = t & 7;
    const int ty = t >> 3;
    const int brow = t >> 4;
    const int bcol4 = (t & 15) * 4;
    const int bcol_src = min(colbase + bcol4, D4 - 4);

    float acc[8][8] = {};
    float4 ca[8], cb[8];
    const float* Ar = &H3[(row0 + t) * H3DIM + kstart];

#pragma unroll
    for (int j = 0; j < 8; j++) {
        ca[j] = *reinterpret_cast<const float4*>(&Ar[j * 4]);
        cb[j] = *reinterpret_cast<const float4*>(&w4[(kstart + brow + j * 4) * D4 + bcol_src]);
    }

    for (int kt = 0; kt < 2; kt++) {
#pragma unroll
        for (int j = 0; j < 8; j++) {
            As[j * 4 + 0][t] = ca[j].x;
            As[j * 4 + 1][t] = ca[j].y;
            As[j * 4 + 2][t] = ca[j].z;
            As[j * 4 + 3][t] = ca[j].w;
            *reinterpret_cast<float4*>(&Bs[brow + j * 4][bcol4]) = cb[j];
        }
        if (kt < 1) {
            const int kn = kstart + 32;
#pragma unroll
            for (int j = 0; j < 8; j++) {
                ca[j] = *reinterpret_cast<const float4*>(&Ar[32 + j * 4]);
                cb[j] = *reinterpret_cast<const float4*>(&w4[(kn + brow + j * 4) * D4 + bcol_src]);
            }
        }
#pragma unroll 8
        for (int kk = 0; kk < 32; kk++) {
            float4 a0 = *reinterpret_cast<const float4*>(&As[kk][ty * 8]);
            float4 a1 = *reinterpret_cast<const float4*>(&As[kk][ty * 8 + 4]);
            float4 b0 = *reinterpret_cast<const float4*>(&Bs[kk][tx * 8]);
            float4 b1 = *reinterpret_cast<const float4*>(&Bs[kk][tx * 8 + 4]);
            float av[8] = {a0.x, a0.y, a0.z, a0.w, a1.x, a1.y, a1.z, a1.w};
            float bv[8] = {b0.x, b0.y, b0.z, b0.w, b1.x, b1.y, b1.z, b1.w};
#pragma unroll
            for (int i = 0; i < 8; i++)
#pragma unroll
                for (int j = 0; j < 8; j++)
                    acc[i][j] += av[i] * bv[j];
        }
    }

    const int pcol0 = colbase + tx * 8;
#pragma unroll
    for (int i = 0; i < 8; i++) {
        const int row = row0 + ty * 8 + i;
        float* pr = &Pd[((size_t)ks * NR + row) * D4 + pcol0];
        if (pcol0 + 4 <= D4)
            *reinterpret_cast<float4*>(&pr[0]) = make_float4(acc[i][0], acc[i][1], acc[i][2], acc[i][3]);
        if (pcol0 + 8 <= D4)
            *reinterpret_cast<float4*>(&pr[4]) = make_float4(acc[i][4], acc[i][5], acc[i][6], acc[i][7]);
    }
}

// ---------------- per-class: ballot-compact -> u64-key rank -> decode(sum Pd) -> NMS --------
__global__ __launch_bounds__(512) void class_nms_kernel(
    const float* __restrict__ probs, const float* __restrict__ Pd,
    const float* __restrict__ b4, const float* __restrict__ rois,
    const float* __restrict__ im_info, float* __restrict__ out)
{
    const int c = blockIdx.x;
    const int t = threadIdx.x;
    const int lane = t & 63;
    const int wave = t >> 6;

    __shared__ float imv[3];
    __shared__ u64   cs_key[NR];
    __shared__ float ss[NR];
    __shared__ int   sx[NR];
    __shared__ float bx[NR][4];
    __shared__ int   kept_pos[NR];
    __shared__ u64 over64[64];
    __shared__ u64 presup_w;
    __shared__ u64 keep_w[16];
    __shared__ int vcount;
    __shared__ int kcount;

    if (t < 3) imv[t] = im_info[t];
    if (t < 16) keep_w[t] = 0ULL;
    if (t == 0) { vcount = 0; kcount = 0; presup_w = 0ULL; }
    __syncthreads();

    for (int i = t; i < NR; i += 512) {
        float s = probs[c * NR + i];
        bool valid = (s > 0.05f);
        u64 m = __ballot(valid ? 1 : 0);
        int wbase = 0;
        if (lane == 0 && m) wbase = atomicAdd(&vcount, __popcll(m));
        wbase = __shfl(wbase, 0, 64);
        if (valid) {
            int p = wbase + __popcll(m & ((1ULL << lane) - 1ULL));
            unsigned int sb = __float_as_uint(s);
            cs_key[p] = ((u64)sb << 32) | (u64)(NR - 1 - i);
        }
    }
    __syncthreads();
    const int V = vcount;

    for (int e = t; e < V; e += 512) {
        const u64 ke = cs_key[e];
        int cnt = 0;
        for (int f = 0; f < V; f++)
            cnt += (cs_key[f] > ke) ? 1 : 0;
        ss[cnt] = __uint_as_float((unsigned int)(ke >> 32));
        sx[cnt] = NR - 1 - (int)(ke & 0xffffffffu);
    }
    __syncthreads();

    const float Hm1 = imv[0] - 1.f, Wm1 = imv[1] - 1.f, inv = 1.f / imv[2];
    for (int i = t; i < V; i += 512) {
        const int r = sx[i];
        float4 dd = *reinterpret_cast<const float4*>(&Pd[(size_t)r * D4 + (c + 1) * 4]);
#pragma unroll
        for (int ksplit = 1; ksplit < SKD; ksplit++) {
            float4 p = *reinterpret_cast<const float4*>(&Pd[((size_t)ksplit * NR + r) * D4 + (c + 1) * 4]);
            dd.x += p.x; dd.y += p.y; dd.z += p.z; dd.w += p.w;
        }
        float4 b4c = *reinterpret_cast<const float4*>(&b4[(c + 1) * 4]);
        float dx = (dd.x + b4c.x) * 0.1f, dy = (dd.y + b4c.y) * 0.1f;
        float dw = (dd.z + b4c.z) * 0.2f, dh = (dd.w + b4c.w) * 0.2f;
        float x1 = rois[r * 5 + 1], y1 = rois[r * 5 + 2];
        float x2 = rois[r * 5 + 3], y2 = rois[r * 5 + 4];
        float wdt = x2 - x1 + 1.f, hgt = y2 - y1 + 1.f;
        float ctx = x1 + 0.5f * wdt, cty = y1 + 0.5f * hgt;
        float pcx = dx * wdt + ctx, pcy = dy * hgt + cty;
        float pw = expf(dw) * wdt, ph = expf(dh) * hgt;
        bx[i][0] = fminf(fmaxf(pcx - 0.5f * pw, 0.f), Wm1) * inv;
        bx[i][1] = fminf(fmaxf(pcy - 0.5f * ph, 0.f), Hm1) * inv;
        bx[i][2] = fminf(fmaxf(pcx + 0.5f * pw, 0.f), Wm1) * inv;
        bx[i][3] = fminf(fmaxf(pcy + 0.5f * ph, 0.f), Hm1) * inv;
    }
    __syncthreads();

    for (int cs = 0; cs < V; cs += 64) {
        const int n = min(64, V - cs);
        const int ksnap = kcount;

        for (int i = wave; i < n; i += 8) {
            const int gi = cs + i;
            const float x1i = bx[gi][0], y1i = bx[gi][1], x2i = bx[gi][2], y2i = bx[gi][3];
            const float ai = (x2i - x1i + 1.f) * (y2i - y1i + 1.f);

            int sup = 0;
            for (int u = lane; u < ksnap; u += 64) {
                const int j = kept_pos[u];
                float iw = fminf(x2i, bx[j][2]) - fmaxf(x1i, bx[j][0]) + 1.f;
                float ih = fminf(y2i, bx[j][3]) - fmaxf(y1i, bx[j][1]) + 1.f;
                if (iw > 0.f && ih > 0.f) {
                    float inter = iw * ih;
                    float aj = (bx[j][2] - bx[j][0] + 1.f) * (bx[j][3] - bx[j][1] + 1.f);
                    if (inter / (ai + aj - inter) > 0.3f) sup = 1;
                }
            }
            int anysup = __any(sup);
            if (anysup && lane == 0) atomicOr(&presup_w, 1ULL << i);

            int pred = 0;
            if (lane < n) {
                const int gj = cs + lane;
                float iw = fminf(x2i, bx[gj][2]) - fmaxf(x1i, bx[gj][0]) + 1.f;
                float ih = fminf(y2i, bx[gj][3]) - fmaxf(y1i, bx[gj][1]) + 1.f;
                if (iw > 0.f && ih > 0.f) {
                    float inter = iw * ih;
                    float aj = (bx[gj][2] - bx[gj][0] + 1.f) * (bx[gj][3] - bx[gj][1] + 1.f);
                    if (inter / (ai + aj - inter) > 0.3f) pred = 1;
                }
            }
            u64 bits = __ballot(pred);
            if (lane == 0) over64[i] = bits;
        }
        __syncthreads();

        if (wave == 0) {
            u64 row = over64[lane];
            unsigned int rlo = (unsigned int)row;
            unsigned int rhi = (unsigned int)(row >> 32);
            u64 validm = (n >= 64) ? ~0ULL : ((1ULL << n) - 1ULL);
            u64 alive = validm & ~presup_w;
            u64 kept = 0ULL;
#pragma unroll
            for (int i = 0; i < 64; i++) {
                u64 ri =
                    ((u64)(unsigned int)__builtin_amdgcn_readlane(rhi, i) << 32) |
                    (unsigned int)__builtin_amdgcn_readlane(rlo, i);
                if ((alive >> i) & 1ULL) { kept |= 1ULL << i; alive &= ~ri; }
            }
            bool mykeep = (kept >> lane) & 1ULL;
            int kb = 0;
            if (lane == 0) {
                keep_w[cs >> 6] = kept;
                presup_w = 0ULL;
                kb = kcount;
                kcount = kb + __popcll(kept);
            }
            kb = __shfl(kb, 0, 64);
            if (mykeep) kept_pos[kb + __popcll(kept & ((1ULL << lane) - 1ULL))] = cs + lane;
        }
        __syncthreads();
    }

    for (int i = t; i < NR; i += 512) {
        float2* o = reinterpret_cast<float2*>(&out[(size_t)(c * NR + i) * 6]);
        bool kp = (i < V) && ((keep_w[i >> 6] >> (i & 63)) & 1ULL);
        float2 p0, p1, p2;
        if (kp) {
            p0 = make_float2(bx[i][0], bx[i][1]);
            p1 = make_float2(bx[i][2], bx[i][3]);
            p2 = make_float2(ss[i], (float)c);
        } else {
            p0 = make_float2(0.f, 0.f);
            p1 = make_float2(0.f, 0.f);
            p2 = make_float2(0.f, 0.f);
        }
        o[0] = p0; o[1] = p1; o[2] = p2;
    }
}

extern "C" void kernel_launch(void* const* d_in, const int* in_sizes, int n_in,
                              void* d_out, int out_size, void* d_ws, size_t ws_size,
                              hipStream_t stream)
{
    const float* X    = (const float*)d_in[0];
    const float* rois = (const float*)d_in[1];
    const float* imi  = (const float*)d_in[2];
    const float* w1   = (const float*)d_in[3];
    const float* b1   = (const float*)d_in[4];
    const float* w2   = (const float*)d_in[5];
    const float* b2   = (const float*)d_in[6];
    const float* w3   = (const float*)d_in[7];
    const float* b3   = (const float*)d_in[8];
    const float* w4   = (const float*)d_in[9];
    const float* b4   = (const float*)d_in[10];
    float* out = (float*)d_out;

    float* ws    = (float*)d_ws;
    float* H3    = ws;                         // 1024*512
    float* probs = H3 + NR * H3DIM;            // 80*1024
    float* P     = probs + NFG * NR;           // SK*1024*768 floats (Pd aliases)

    // SK=8 needs 27.6MB of ws; fall back to SK=4 otherwise (deterministic: ws_size fixed).
    const size_t need8 = ((size_t)NR * H3DIM + (size_t)NFG * NR + 8ULL * NR * NCOMB) * sizeof(float);

    if (ws_size >= need8) {
        gemm_main_kernel<8><<<1536, 256, 0, stream>>>(X, w1, w3, P);
        mid_kernel<8><<<2048, 128, 0, stream>>>(P, b1, b3, w2, b2, H3, probs);
    } else {
        gemm_main_kernel<4><<<768, 256, 0, stream>>>(X, w1, w3, P);
        mid_kernel<4><<<2048, 128, 0, stream>>>(P, b1, b3, w2, b2, H3, probs);
    }
    gemm_delta_kernel<<<dim3(6, 16, SKD), 64, 0, stream>>>(H3, w4, P);
    class_nms_kernel<<<NFG, 512, 0, stream>>>(probs, P, b4, rois, imi, out);
}

// Round 25
// 140.892 us; speedup vs baseline: 1.0293x; 1.0293x over previous
//
#include <hip/hip_runtime.h>

#define NR 1024        // num rois
#define NFG 80         // fg classes
#define CC 81          // total classes
#define KDIM 2048
#define H1DIM 256
#define H3DIM 512
#define D4 324         // 4*81
#define NCOMB 768      // 256 + 512 combined output cols
#define SKM 4          // split-K for main GEMM (K=2048 -> 512/block, 128/wave)
#define SKD 8          // split-K for deltas GEMM (K=512 -> 64/chunk)

typedef unsigned long long u64;

// ---------------- main GEMM partials: P[ks][1024][768] = X @ [w1|w3] (K-chunk ks) ----------
// CONVERGED r23 config: 4-wave blocks, wave wv owns K-quarter (128), BK=16 sub-tiles ->
// 8KB LDS/wave, 32KB/block, 3 blocks/CU = 12 waves/CU. Private per-wave LDS, no inner
// barriers; deterministic tree-combine epilogue; XCD-chunked swizzle.
// (Tested and rejected: reg-prefetch pin r17, SK=8 r14/r24, M32 tiles r20, barrier
// variants r12/r13 — all regressed or neutral vs this config.)
__global__ __launch_bounds__(256) void gemm_main_kernel(
    const float* __restrict__ X, const float* __restrict__ w1,
    const float* __restrict__ w3, float* __restrict__ P)
{
    const int bid = blockIdx.x;            // 0..767
    const int swz = (bid & 7) * 96 + (bid >> 3);
    const int nb = swz % 12;
    const int mb = (swz / 12) & 15;
    const int ks = swz / 192;

    const float* B; int Ncols, colbase;
    if (nb < 4) { B = w1; Ncols = H1DIM; colbase = nb * 64; }
    else        { B = w3; Ncols = H3DIM; colbase = (nb - 4) * 64; }
    const int row0 = mb * 64;
    const int wv = threadIdx.x >> 6;       // 0..3
    const int lane = threadIdx.x & 63;
    const int kstart = ks * 512 + wv * 128;

    __shared__ float L[4][2048];           // per-wave 8KB: [0..1023]=As(16x64 [k][m]), [1024..]=Bs
    float* Asw = L[wv];
    float* Bsw = L[wv] + 1024;

    const int tx = lane & 7;
    const int ty = lane >> 3;
    const int rg = lane & 15;              // A staging: 4-row group
    const int kg = lane >> 4;              // A staging: k-quad group (0..3)
    const int brow = lane >> 4;            // B staging row group
    const int bcol4 = (lane & 15) * 4;

    float acc[8][8] = {};
    float4 ca[4], cb[4];

#pragma unroll
    for (int rr = 0; rr < 4; rr++)
        ca[rr] = *reinterpret_cast<const float4*>(
            &X[(size_t)(row0 + rg * 4 + rr) * KDIM + kstart + kg * 4]);
#pragma unroll
    for (int j = 0; j < 4; j++)
        cb[j] = *reinterpret_cast<const float4*>(
            &B[(size_t)(kstart + brow + j * 4) * Ncols + colbase + bcol4]);

    for (int kt = 0; kt < 8; kt++) {
        // stage A: in-register 4x4 transpose -> [k][m]; stage B rows
        {
            const int kb = kg * 4;
            float4 w0 = make_float4(ca[0].x, ca[1].x, ca[2].x, ca[3].x);
            float4 w1_ = make_float4(ca[0].y, ca[1].y, ca[2].y, ca[3].y);
            float4 w2_ = make_float4(ca[0].z, ca[1].z, ca[2].z, ca[3].z);
            float4 w3_ = make_float4(ca[0].w, ca[1].w, ca[2].w, ca[3].w);
            *reinterpret_cast<float4*>(&Asw[(kb + 0) * 64 + rg * 4]) = w0;
            *reinterpret_cast<float4*>(&Asw[(kb + 1) * 64 + rg * 4]) = w1_;
            *reinterpret_cast<float4*>(&Asw[(kb + 2) * 64 + rg * 4]) = w2_;
            *reinterpret_cast<float4*>(&Asw[(kb + 3) * 64 + rg * 4]) = w3_;
        }
#pragma unroll
        for (int j = 0; j < 4; j++)
            *reinterpret_cast<float4*>(&Bsw[(brow + j * 4) * 64 + bcol4]) = cb[j];

        if (kt < 7) {
            const int kof = kstart + (kt + 1) * 16;
#pragma unroll
            for (int rr = 0; rr < 4; rr++)
                ca[rr] = *reinterpret_cast<const float4*>(
                    &X[(size_t)(row0 + rg * 4 + rr) * KDIM + kof + kg * 4]);
#pragma unroll
            for (int j = 0; j < 4; j++)
                cb[j] = *reinterpret_cast<const float4*>(
                    &B[(size_t)(kof + brow + j * 4) * Ncols + colbase + bcol4]);
        }

#pragma unroll 8
        for (int kk = 0; kk < 16; kk++) {
            float4 a0 = *reinterpret_cast<const float4*>(&Asw[kk * 64 + ty * 8]);
            float4 a1 = *reinterpret_cast<const float4*>(&Asw[kk * 64 + ty * 8 + 4]);
            float4 b0 = *reinterpret_cast<const float4*>(&Bsw[kk * 64 + tx * 8]);
            float4 b1 = *reinterpret_cast<const float4*>(&Bsw[kk * 64 + tx * 8 + 4]);
            float av[8] = {a0.x, a0.y, a0.z, a0.w, a1.x, a1.y, a1.z, a1.w};
            float bv[8] = {b0.x, b0.y, b0.z, b0.w, b1.x, b1.y, b1.z, b1.w};
#pragma unroll
            for (int i = 0; i < 8; i++)
#pragma unroll
                for (int j = 0; j < 8; j++)
                    acc[i][j] += av[i] * bv[j];
        }
    }

    // deterministic tree-combine: (w0+w1) + (w2+w3), then w0 stores.
    float* buf0 = &L[0][0];
    float* buf1 = &L[2][0];
    __syncthreads();
    if (wv == 1 || wv == 3) {
        float* dst = (wv == 1) ? buf0 : buf1;
#pragma unroll
        for (int i = 0; i < 8; i++) {
            const int row = ty * 8 + i;
            *reinterpret_cast<float4*>(&dst[row * 64 + tx * 8]) =
                make_float4(acc[i][0], acc[i][1], acc[i][2], acc[i][3]);
            *reinterpret_cast<float4*>(&dst[row * 64 + tx * 8 + 4]) =
                make_float4(acc[i][4], acc[i][5], acc[i][6], acc[i][7]);
        }
    }
    __syncthreads();
    if (wv == 0 || wv == 2) {
        const float* src = (wv == 0) ? buf0 : buf1;
#pragma unroll
        for (int i = 0; i < 8; i++) {
            const int row = ty * 8 + i;
            float4 c0 = *reinterpret_cast<const float4*>(&src[row * 64 + tx * 8]);
            float4 c1 = *reinterpret_cast<const float4*>(&src[row * 64 + tx * 8 + 4]);
            acc[i][0] += c0.x; acc[i][1] += c0.y; acc[i][2] += c0.z; acc[i][3] += c0.w;
            acc[i][4] += c1.x; acc[i][5] += c1.y; acc[i][6] += c1.z; acc[i][7] += c1.w;
        }
    }
    __syncthreads();
    if (wv == 2) {
#pragma unroll
        for (int i = 0; i < 8; i++) {
            const int row = ty * 8 + i;
            *reinterpret_cast<float4*>(&buf0[row * 64 + tx * 8]) =
                make_float4(acc[i][0], acc[i][1], acc[i][2], acc[i][3]);
            *reinterpret_cast<float4*>(&buf0[row * 64 + tx * 8 + 4]) =
                make_float4(acc[i][4], acc[i][5], acc[i][6], acc[i][7]);
        }
    }
    __syncthreads();
    if (wv == 0) {
        const int ccol = nb * 64 + tx * 8;
#pragma unroll
        for (int i = 0; i < 8; i++) {
            const int row = ty * 8 + i;
            float4 c0 = *reinterpret_cast<const float4*>(&buf0[row * 64 + tx * 8]);
            float4 c1 = *reinterpret_cast<const float4*>(&buf0[row * 64 + tx * 8 + 4]);
            float* pr = &P[((size_t)ks * NR + row0 + row) * NCOMB + ccol];
            *reinterpret_cast<float4*>(&pr[0]) = make_float4(
                acc[i][0] + c0.x, acc[i][1] + c0.y, acc[i][2] + c0.z, acc[i][3] + c0.w);
            *reinterpret_cast<float4*>(&pr[4]) = make_float4(
                acc[i][4] + c1.x, acc[i][5] + c1.y, acc[i][6] + c1.z, acc[i][7] + c1.w);
        }
    }
}

// ---------------- mid: blocks 0..1023 reduce H3; blocks 1024..2047 scores+softmax ----------
__global__ __launch_bounds__(128) void mid_kernel(
    const float* __restrict__ P, const float* __restrict__ b1,
    const float* __restrict__ b3, const float* __restrict__ w2,
    const float* __restrict__ b2, float* __restrict__ H3,
    float* __restrict__ probs)
{
    const int t = threadIdx.x;

    if (blockIdx.x < 1024) {
        const int idx = blockIdx.x * 128 + t;
        const int row = idx / (H3DIM / 4);
        const int col = (idx % (H3DIM / 4)) * 4;
        const size_t off = (size_t)row * NCOMB + H1DIM + col;
        float4 s = *reinterpret_cast<const float4*>(&P[off]);
#pragma unroll
        for (int ksplit = 1; ksplit < SKM; ksplit++) {
            float4 p = *reinterpret_cast<const float4*>(&P[(size_t)ksplit * NR * NCOMB + off]);
            s.x += p.x; s.y += p.y; s.z += p.z; s.w += p.w;
        }
        float4 bb = *reinterpret_cast<const float4*>(&b3[col]);
        s.x = fmaxf(s.x + bb.x, 0.f); s.y = fmaxf(s.y + bb.y, 0.f);
        s.z = fmaxf(s.z + bb.z, 0.f); s.w = fmaxf(s.w + bb.w, 0.f);
        *reinterpret_cast<float4*>(&H3[row * H3DIM + col]) = s;
        return;
    }

    const int r = blockIdx.x - 1024;
    __shared__ float h[H1DIM];
    __shared__ float lg[CC];
    __shared__ float red[128];

    for (int k = t; k < H1DIM; k += 128) {
        float s = P[(size_t)r * NCOMB + k];
#pragma unroll
        for (int ksplit = 1; ksplit < SKM; ksplit++)
            s += P[((size_t)ksplit * NR + r) * NCOMB + k];
        h[k] = fmaxf(s + b1[k], 0.f);
    }
    __syncthreads();

    if (t < CC) {
        float acc = b2[t];
        for (int k = 0; k < H1DIM; k++) acc += h[k] * w2[k * CC + t];
        lg[t] = acc;
    }
    __syncthreads();

    red[t] = (t < CC) ? lg[t] : -1e30f;
    __syncthreads();
    for (int s = 64; s > 0; s >>= 1) {
        if (t < s) red[t] = fmaxf(red[t], red[t + s]);
        __syncthreads();
    }
    float mx = red[0];
    __syncthreads();

    float e = 0.f;
    if (t < CC) e = expf(lg[t] - mx);
    red[t] = e;
    __syncthreads();
    for (int s = 64; s > 0; s >>= 1) {
        if (t < s) red[t] += red[t + s];
        __syncthreads();
    }
    float sum = red[0];

    if (t >= 1 && t < CC) probs[(t - 1) * NR + r] = e / sum;
}

// ---------------- deltas GEMM partials: Pd[ks][1024][324] = H3 @ w4 ----------
__global__ __launch_bounds__(64) void gemm_delta_kernel(
    const float* __restrict__ H3, const float* __restrict__ w4, float* __restrict__ Pd)
{
    const int nb = blockIdx.x;
    const int mb = blockIdx.y;
    const int ks = blockIdx.z;
    const int colbase = nb * 64;
    const int row0 = mb * 64;
    const int kstart = ks * 64;

    __shared__ float As[32][64];
    __shared__ float Bs[32][64];
    const int t = threadIdx.x;
    const int tx = t & 7;
    const int ty = t >> 3;
    const int brow = t >> 4;
    const int bcol4 = (t & 15) * 4;
    const int bcol_src = min(colbase + bcol4, D4 - 4);

    float acc[8][8] = {};
    float4 ca[8], cb[8];
    const float* Ar = &H3[(row0 + t) * H3DIM + kstart];

#pragma unroll
    for (int j = 0; j < 8; j++) {
        ca[j] = *reinterpret_cast<const float4*>(&Ar[j * 4]);
        cb[j] = *reinterpret_cast<const float4*>(&w4[(kstart + brow + j * 4) * D4 + bcol_src]);
    }

    for (int kt = 0; kt < 2; kt++) {
#pragma unroll
        for (int j = 0; j < 8; j++) {
            As[j * 4 + 0][t] = ca[j].x;
            As[j * 4 + 1][t] = ca[j].y;
            As[j * 4 + 2][t] = ca[j].z;
            As[j * 4 + 3][t] = ca[j].w;
            *reinterpret_cast<float4*>(&Bs[brow + j * 4][bcol4]) = cb[j];
        }
        if (kt < 1) {
            const int kn = kstart + 32;
#pragma unroll
            for (int j = 0; j < 8; j++) {
                ca[j] = *reinterpret_cast<const float4*>(&Ar[32 + j * 4]);
                cb[j] = *reinterpret_cast<const float4*>(&w4[(kn + brow + j * 4) * D4 + bcol_src]);
            }
        }
#pragma unroll 8
        for (int kk = 0; kk < 32; kk++) {
            float4 a0 = *reinterpret_cast<const float4*>(&As[kk][ty * 8]);
            float4 a1 = *reinterpret_cast<const float4*>(&As[kk][ty * 8 + 4]);
            float4 b0 = *reinterpret_cast<const float4*>(&Bs[kk][tx * 8]);
            float4 b1 = *reinterpret_cast<const float4*>(&Bs[kk][tx * 8 + 4]);
            float av[8] = {a0.x, a0.y, a0.z, a0.w, a1.x, a1.y, a1.z, a1.w};
            float bv[8] = {b0.x, b0.y, b0.z, b0.w, b1.x, b1.y, b1.z, b1.w};
#pragma unroll
            for (int i = 0; i < 8; i++)
#pragma unroll
                for (int j = 0; j < 8; j++)
                    acc[i][j] += av[i] * bv[j];
        }
    }

    const int pcol0 = colbase + tx * 8;
#pragma unroll
    for (int i = 0; i < 8; i++) {
        const int row = row0 + ty * 8 + i;
        float* pr = &Pd[((size_t)ks * NR + row) * D4 + pcol0];
        if (pcol0 + 4 <= D4)
            *reinterpret_cast<float4*>(&pr[0]) = make_float4(acc[i][0], acc[i][1], acc[i][2], acc[i][3]);
        if (pcol0 + 8 <= D4)
            *reinterpret_cast<float4*>(&pr[4]) = make_float4(acc[i][4], acc[i][5], acc[i][6], acc[i][7]);
    }
}

// ---------------- per-class: ballot-compact -> u64-key rank -> decode(sum Pd) -> NMS --------
__global__ __launch_bounds__(512) void class_nms_kernel(
    const float* __restrict__ probs, const float* __restrict__ Pd,
    const float* __restrict__ b4, const float* __restrict__ rois,
    const float* __restrict__ im_info, float* __restrict__ out)
{
    const int c = blockIdx.x;
    const int t = threadIdx.x;
    const int lane = t & 63;
    const int wave = t >> 6;

    __shared__ float imv[3];
    __shared__ u64   cs_key[NR];
    __shared__ float ss[NR];
    __shared__ int   sx[NR];
    __shared__ float bx[NR][4];
    __shared__ int   kept_pos[NR];
    __shared__ u64 over64[64];
    __shared__ u64 presup_w;
    __shared__ u64 keep_w[16];
    __shared__ int vcount;
    __shared__ int kcount;

    if (t < 3) imv[t] = im_info[t];
    if (t < 16) keep_w[t] = 0ULL;
    if (t == 0) { vcount = 0; kcount = 0; presup_w = 0ULL; }
    __syncthreads();

    for (int i = t; i < NR; i += 512) {
        float s = probs[c * NR + i];
        bool valid = (s > 0.05f);
        u64 m = __ballot(valid ? 1 : 0);
        int wbase = 0;
        if (lane == 0 && m) wbase = atomicAdd(&vcount, __popcll(m));
        wbase = __shfl(wbase, 0, 64);
        if (valid) {
            int p = wbase + __popcll(m & ((1ULL << lane) - 1ULL));
            unsigned int sb = __float_as_uint(s);
            cs_key[p] = ((u64)sb << 32) | (u64)(NR - 1 - i);
        }
    }
    __syncthreads();
    const int V = vcount;

    for (int e = t; e < V; e += 512) {
        const u64 ke = cs_key[e];
        int cnt = 0;
        for (int f = 0; f < V; f++)
            cnt += (cs_key[f] > ke) ? 1 : 0;
        ss[cnt] = __uint_as_float((unsigned int)(ke >> 32));
        sx[cnt] = NR - 1 - (int)(ke & 0xffffffffu);
    }
    __syncthreads();

    const float Hm1 = imv[0] - 1.f, Wm1 = imv[1] - 1.f, inv = 1.f / imv[2];
    for (int i = t; i < V; i += 512) {
        const int r = sx[i];
        float4 dd = *reinterpret_cast<const float4*>(&Pd[(size_t)r * D4 + (c + 1) * 4]);
#pragma unroll
        for (int ksplit = 1; ksplit < SKD; ksplit++) {
            float4 p = *reinterpret_cast<const float4*>(&Pd[((size_t)ksplit * NR + r) * D4 + (c + 1) * 4]);
            dd.x += p.x; dd.y += p.y; dd.z += p.z; dd.w += p.w;
        }
        float4 b4c = *reinterpret_cast<const float4*>(&b4[(c + 1) * 4]);
        float dx = (dd.x + b4c.x) * 0.1f, dy = (dd.y + b4c.y) * 0.1f;
        float dw = (dd.z + b4c.z) * 0.2f, dh = (dd.w + b4c.w) * 0.2f;
        float x1 = rois[r * 5 + 1], y1 = rois[r * 5 + 2];
        float x2 = rois[r * 5 + 3], y2 = rois[r * 5 + 4];
        float wdt = x2 - x1 + 1.f, hgt = y2 - y1 + 1.f;
        float ctx = x1 + 0.5f * wdt, cty = y1 + 0.5f * hgt;
        float pcx = dx * wdt + ctx, pcy = dy * hgt + cty;
        float pw = expf(dw) * wdt, ph = expf(dh) * hgt;
        bx[i][0] = fminf(fmaxf(pcx - 0.5f * pw, 0.f), Wm1) * inv;
        bx[i][1] = fminf(fmaxf(pcy - 0.5f * ph, 0.f), Hm1) * inv;
        bx[i][2] = fminf(fmaxf(pcx + 0.5f * pw, 0.f), Wm1) * inv;
        bx[i][3] = fminf(fmaxf(pcy + 0.5f * ph, 0.f), Hm1) * inv;
    }
    __syncthreads();

    for (int cs = 0; cs < V; cs += 64) {
        const int n = min(64, V - cs);
        const int ksnap = kcount;

        for (int i = wave; i < n; i += 8) {
            const int gi = cs + i;
            const float x1i = bx[gi][0], y1i = bx[gi][1], x2i = bx[gi][2], y2i = bx[gi][3];
            const float ai = (x2i - x1i + 1.f) * (y2i - y1i + 1.f);

            int sup = 0;
            for (int u = lane; u < ksnap; u += 64) {
                const int j = kept_pos[u];
                float iw = fminf(x2i, bx[j][2]) - fmaxf(x1i, bx[j][0]) + 1.f;
                float ih = fminf(y2i, bx[j][3]) - fmaxf(y1i, bx[j][1]) + 1.f;
                if (iw > 0.f && ih > 0.f) {
                    float inter = iw * ih;
                    float aj = (bx[j][2] - bx[j][0] + 1.f) * (bx[j][3] - bx[j][1] + 1.f);
                    if (inter / (ai + aj - inter) > 0.3f) sup = 1;
                }
            }
            int anysup = __any(sup);
            if (anysup && lane == 0) atomicOr(&presup_w, 1ULL << i);

            int pred = 0;
            if (lane < n) {
                const int gj = cs + lane;
                float iw = fminf(x2i, bx[gj][2]) - fmaxf(x1i, bx[gj][0]) + 1.f;
                float ih = fminf(y2i, bx[gj][3]) - fmaxf(y1i, bx[gj][1]) + 1.f;
                if (iw > 0.f && ih > 0.f) {
                    float inter = iw * ih;
                    float aj = (bx[gj][2] - bx[gj][0] + 1.f) * (bx[gj][3] - bx[gj][1] + 1.f);
                    if (inter / (ai + aj - inter) > 0.3f) pred = 1;
                }
            }
            u64 bits = __ballot(pred);
            if (lane == 0) over64[i] = bits;
        }
        __syncthreads();

        if (wave == 0) {
            u64 row = over64[lane];
            unsigned int rlo = (unsigned int)row;
            unsigned int rhi = (unsigned int)(row >> 32);
            u64 validm = (n >= 64) ? ~0ULL : ((1ULL << n) - 1ULL);
            u64 alive = validm & ~presup_w;
            u64 kept = 0ULL;
#pragma unroll
            for (int i = 0; i < 64; i++) {
                u64 ri =
                    ((u64)(unsigned int)__builtin_amdgcn_readlane(rhi, i) << 32) |
                    (unsigned int)__builtin_amdgcn_readlane(rlo, i);
                if ((alive >> i) & 1ULL) { kept |= 1ULL << i; alive &= ~ri; }
            }
            bool mykeep = (kept >> lane) & 1ULL;
            int kb = 0;
            if (lane == 0) {
                keep_w[cs >> 6] = kept;
                presup_w = 0ULL;
                kb = kcount;
                kcount = kb + __popcll(kept);
            }
            kb = __shfl(kb, 0, 64);
            if (mykeep) kept_pos[kb + __popcll(kept & ((1ULL << lane) - 1ULL))] = cs + lane;
        }
        __syncthreads();
    }

    for (int i = t; i < NR; i += 512) {
        float2* o = reinterpret_cast<float2*>(&out[(size_t)(c * NR + i) * 6]);
        bool kp = (i < V) && ((keep_w[i >> 6] >> (i & 63)) & 1ULL);
        float2 p0, p1, p2;
        if (kp) {
            p0 = make_float2(bx[i][0], bx[i][1]);
            p1 = make_float2(bx[i][2], bx[i][3]);
            p2 = make_float2(ss[i], (float)c);
        } else {
            p0 = make_float2(0.f, 0.f);
            p1 = make_float2(0.f, 0.f);
            p2 = make_float2(0.f, 0.f);
        }
        o[0] = p0; o[1] = p1; o[2] = p2;
    }
}

extern "C" void kernel_launch(void* const* d_in, const int* in_sizes, int n_in,
                              void* d_out, int out_size, void* d_ws, size_t ws_size,
                              hipStream_t stream)
{
    const float* X    = (const float*)d_in[0];
    const float* rois = (const float*)d_in[1];
    const float* imi  = (const float*)d_in[2];
    const float* w1   = (const float*)d_in[3];
    const float* b1   = (const float*)d_in[4];
    const float* w2   = (const float*)d_in[5];
    const float* b2   = (const float*)d_in[6];
    const float* w3   = (const float*)d_in[7];
    const float* b3   = (const float*)d_in[8];
    const float* w4   = (const float*)d_in[9];
    const float* b4   = (const float*)d_in[10];
    float* out = (float*)d_out;

    float* ws    = (float*)d_ws;
    float* H3    = ws;                         // 1024*512
    float* probs = H3 + NR * H3DIM;            // 80*1024
    float* P     = probs + NFG * NR;           // 4*1024*768 floats (Pd aliases)

    gemm_main_kernel<<<768, 256, 0, stream>>>(X, w1, w3, P);
    mid_kernel<<<2048, 128, 0, stream>>>(P, b1, b3, w2, b2, H3, probs);
    gemm_delta_kernel<<<dim3(6, 16, SKD), 64, 0, stream>>>(H3, w4, P);
    class_nms_kernel<<<NFG, 512, 0, stream>>>(probs, P, b4, rois, imi, out);
}